// Round 1
// baseline (26.683 us; speedup 1.0000x reference)
//
#include <hip/hip_runtime.h>

// TransientGenerator: out[b, p] = sum over transients j of batch b with
// t_sample_j <= p < t_sample_j + L of gain_j * template[id_j][p - t_sample_j].
// Gather formulation (no atomics, no zeroing pass): one block per
// (batch, 1024-sample chunk); sorted t_sample in LDS -> binary search + early break.

constexpr int SR    = 16000;  // SAMPLE_RATE (reference constant)
constexpr int TL    = 1600;   // TRANSIENT_SAMPLES (reference constant)
constexpr int MAXT  = 256;    // MAX_TRANSIENTS (reference constant)
constexpr int CHUNK = 1024;   // samples per block = 256 threads * 4

__global__ __launch_bounds__(256)
void transient_gather(const float* __restrict__ timings,   // [B,T]
                      const int*   __restrict__ ids,       // [B,T]
                      const float* __restrict__ gains,     // [B,T]
                      const float* __restrict__ templates, // [n_tr,TL]
                      float*       __restrict__ out,       // [B,A]
                      int T, int n_tr, int A, int bpb)
{
    __shared__ int   s_ts[MAXT];
    __shared__ float s_g [MAXT];
    __shared__ int   s_id[MAXT];

    const int b     = blockIdx.x / bpb;
    const int chunk = (blockIdx.x - b * bpb) * CHUNK;

    const float* bt = timings + (size_t)b * T;
    const float* bg = gains   + (size_t)b * T;
    const int*   bi = ids     + (size_t)b * T;

    // Stage per-batch transient metadata into LDS (T <= MAXT).
    for (int j = threadIdx.x; j < T; j += blockDim.x) {
        const float tm = bt[j];
        const int   ts = (int)floorf(tm * (float)SR);  // matches jnp.floor(t*SR) in fp32
        float g  = bg[j];
        int   id = bi[j];
        const bool ok = (g > 0.0f) & (id >= 0) & (id < n_tr) & (ts < A);
        s_ts[j] = ts;                 // keep ts even if invalid: preserves sorted order
        s_g [j] = ok ? g : 0.0f;      // invalid -> zero contribution (reference 'valid' mask)
        s_id[j] = ok ? id : 0;
    }
    __syncthreads();

    const int p0 = chunk + (int)threadIdx.x * 4;   // this thread's 4 samples
    float acc[4] = {0.f, 0.f, 0.f, 0.f};

    const int chunk_end = chunk + CHUNK;
    // First j whose t_sample could still overlap this chunk: s_ts[j] >= chunk - TL + 1.
    // Block-uniform binary search over sorted s_ts.
    int lo = 0, hi = T;
    const int key = chunk - TL + 1;
    while (lo < hi) { const int m = (lo + hi) >> 1; if (s_ts[m] < key) lo = m + 1; else hi = m; }

    for (int j = lo; j < T; ++j) {
        const int ts = s_ts[j];
        if (ts >= chunk_end) break;                 // sorted: nothing later overlaps
        const float g = s_g[j];
        const float* __restrict__ row = templates + (size_t)s_id[j] * TL;
        const int off = p0 - ts;                    // offset of sample p0 into the template
        if (off >= 0 && off + 3 < TL) {
#pragma unroll
            for (int k = 0; k < 4; ++k) acc[k] += g * row[off + k];
        } else {
#pragma unroll
            for (int k = 0; k < 4; ++k) {
                const int o = off + k;
                if (o >= 0 && o < TL) acc[k] += g * row[o];
            }
        }
    }

    float* op = out + (size_t)b * A + p0;
    if (p0 + 3 < A && ((((size_t)op) & 15) == 0)) {
        *reinterpret_cast<float4*>(op) = make_float4(acc[0], acc[1], acc[2], acc[3]);
    } else {
#pragma unroll
        for (int k = 0; k < 4; ++k) if (p0 + k < A) op[k] = acc[k];
    }
}

extern "C" void kernel_launch(void* const* d_in, const int* in_sizes, int n_in,
                              void* d_out, int out_size, void* d_ws, size_t ws_size,
                              hipStream_t stream) {
    const float* timings   = (const float*)d_in[0];
    const int*   ids       = (const int*)  d_in[1];
    const float* gains     = (const float*)d_in[2];
    const float* templates = (const float*)d_in[3];
    float*       out       = (float*)d_out;

    // Structural constants from the reference: T (MAX_TRANSIENTS), TL (template len).
    const int T    = MAXT;                 // in_sizes[0] = B*T
    const int B    = in_sizes[0] / T;
    const int n_tr = in_sizes[3] / TL;     // templates are [n_tr, TL]
    const int A    = out_size / B;         // audio_length
    const int bpb  = (A + CHUNK - 1) / CHUNK;

    dim3 grid(B * bpb), block(256);
    transient_gather<<<grid, block, 0, stream>>>(timings, ids, gains, templates, out,
                                                 T, n_tr, A, bpb);
}